// Round 14
// baseline (389.343 us; speedup 1.0000x reference)
//
#include <hip/hip_runtime.h>

typedef unsigned short ushort_t;
typedef unsigned int uint_t;
typedef __attribute__((ext_vector_type(8))) short short8;   // 8 x bf16 bits
typedef __attribute__((ext_vector_type(4))) float f32x4;
typedef __attribute__((ext_vector_type(4))) unsigned short ushort4_t;
typedef __attribute__((ext_vector_type(4))) unsigned int uint4_t;

__device__ inline ushort_t f2b(float f) {
    unsigned int x = __builtin_bit_cast(unsigned int, f);
    x += 0x7fffu + ((x >> 16) & 1u);   // RNE
    return (ushort_t)(x >> 16);
}
__device__ inline uint_t cvt_pk_bf16(float lo, float hi) {
    uint_t r;
    asm("v_cvt_pk_bf16_f32 %0, %1, %2" : "=v"(r) : "v"(lo), "v"(hi));
    return r;   // low16 = bf16(lo), high16 = bf16(hi)
}

__device__ inline void gload16(const void* g, void* l) {
    __builtin_amdgcn_global_load_lds(
        (const __attribute__((address_space(1))) void*)g,
        (__attribute__((address_space(3))) void*)l, 16, 0, 0);
}

// ---------------- fp32 -> bf16 cast (8 elems/thread) ----------------
__global__ __launch_bounds__(256)
void cast_bf16(const float* __restrict__ src, ushort_t* __restrict__ dst) {
    size_t i = ((size_t)blockIdx.x * 256 + threadIdx.x) * 8;
    f32x4 a = *reinterpret_cast<const f32x4*>(src + i);
    f32x4 b = *reinterpret_cast<const f32x4*>(src + i + 4);
    short8 v;
#pragma unroll
    for (int j = 0; j < 4; ++j) { v[j] = (short)f2b(a[j]); v[4 + j] = (short)f2b(b[j]); }
    *reinterpret_cast<short8*>(dst + i) = v;
}

// ---------------- batched 2048x2048 fp32->bf16 transpose (4 weight matrices) ----------------
__global__ __launch_bounds__(64)
void transp4(const float* __restrict__ s0, const float* __restrict__ s1,
             const float* __restrict__ s2, const float* __restrict__ s3,
             ushort_t* __restrict__ d0, ushort_t* __restrict__ d1,
             ushort_t* __restrict__ d2, ushort_t* __restrict__ d3) {
    const int z = blockIdx.z;
    const float* src = (z == 0) ? s0 : (z == 1) ? s1 : (z == 2) ? s2 : s3;
    ushort_t* dst = (z == 0) ? d0 : (z == 1) ? d1 : (z == 2) ? d2 : d3;
    const int R = 2048, C = 2048;
    int r0 = blockIdx.x * 64 + ((threadIdx.x >> 3) << 3);
    int c0 = blockIdx.y * 64 + ((threadIdx.x & 7) << 3);
    ushort_t v[8][8];
#pragma unroll
    for (int i = 0; i < 8; ++i) {
        const float* p = src + (size_t)(r0 + i) * C + c0;
        f32x4 a = *reinterpret_cast<const f32x4*>(p);
        f32x4 b = *reinterpret_cast<const f32x4*>(p + 4);
#pragma unroll
        for (int j = 0; j < 4; ++j) { v[i][j] = f2b(a[j]); v[i][4 + j] = f2b(b[j]); }
    }
#pragma unroll
    for (int c = 0; c < 8; ++c) {
        short8 w;
#pragma unroll
        for (int i = 0; i < 8; ++i) w[i] = (short)v[i][c];
        *reinterpret_cast<short8*>(dst + (size_t)(c0 + c) * R + r0) = w;
    }
}

// ---------------- phase-split pipelined GEMM: BM=128 x BN=256, BK=64, 8 waves (2Mx4N) ----------------
// Triple-buffered LDS (144KB), depth-2 tile prefetch, counted vmcnt(6), and per-K-tile
// TWO barrier-fenced phases: {stage-chunk || ds_read -> barrier -> MFMA cluster -> barrier}.
// Grid (N/256, M/128) = (8,32) = 256 blocks = 1/CU.
// MODE 0: rope(+oscale) -> [B,H,T,D] bf16; MODE 2: V^T -> [B,H,D,T]; MODE 3: fp32 linear.
template <int MODE>
__global__ __launch_bounds__(512)
void gemm_p(const ushort_t* __restrict__ A, const ushort_t* __restrict__ Bt,
            const float* __restrict__ bias, void* __restrict__ Cv, float oscale) {
    const int K = 2048;
    __shared__ __align__(16) ushort_t As[3][128 * 64];
    __shared__ __align__(16) ushort_t Bs[3][256 * 64];
    const int tid = threadIdx.x, lane = tid & 63, wid = tid >> 6;
    const int l15 = lane & 15, g = lane >> 4;
    const int wr = wid >> 2, wc = wid & 3;          // 2M x 4N wave grid, per-wave 64x64
    const int m0 = blockIdx.y * 128, n0 = blockIdx.x * 256;

    // stage a K-tile in two chunks: part 0 = A(2/thread) + B is=0 ; part 1 = B is=1..2
    auto stage_part = [&](int t, int buf, int part) {
        const int k0 = t << 6;
        if (part == 0) {
#pragma unroll
            for (int is = 0; is < 2; ++is) {        // A: 1024 chunks, 2/thread
                int c = is * 512 + tid;
                int row = c >> 3, sub = c & 7;
                int ks = (sub ^ (row & 7)) << 3;    // pre-swizzled source (involution)
                gload16(A + (size_t)(m0 + row) * K + k0 + ks, (char*)As[buf] + (size_t)c * 16);
            }
            {   // B chunk 0 of 4
                int c = tid;
                int row = c >> 3, sub = c & 7;
                int ks = (sub ^ (row & 7)) << 3;
                gload16(Bt + (size_t)(n0 + row) * K + k0 + ks, (char*)Bs[buf] + (size_t)c * 16);
            }
        } else {
#pragma unroll
            for (int is = 1; is < 4; ++is) {        // B chunks 1..3
                int c = is * 512 + tid;
                int row = c >> 3, sub = c & 7;
                int ks = (sub ^ (row & 7)) << 3;
                gload16(Bt + (size_t)(n0 + row) * K + k0 + ks, (char*)Bs[buf] + (size_t)c * 16);
            }
        }
    };

    f32x4 acc[4][4] = {};
    stage_part(0, 0, 0); stage_part(0, 0, 1);
    stage_part(1, 1, 0); stage_part(1, 1, 1);
    asm volatile("s_waitcnt vmcnt(6)" ::: "memory");   // tile0 landed; tile1 in flight
    __builtin_amdgcn_s_barrier();

    int buf = 0, bufn = 2;
    for (int t = 0; t < 32; ++t) {
#pragma unroll
        for (int kk = 0; kk < 2; ++kk) {
            // phase: stage-chunk || ds_read, then barrier-fenced MFMA cluster
            if (t < 30) stage_part(t + 2, bufn, kk);
            short8 af[4], bf[4];
#pragma unroll
            for (int i = 0; i < 4; ++i) {
                int ra = wr * 64 + i * 16 + l15;
                af[i] = *reinterpret_cast<const short8*>(
                    (const char*)As[buf] + ra * 128 + (((4 * kk + g) ^ (ra & 7)) << 4));
                int rb = wc * 64 + i * 16 + l15;
                bf[i] = *reinterpret_cast<const short8*>(
                    (const char*)Bs[buf] + rb * 128 + (((4 * kk + g) ^ (rb & 7)) << 4));
            }
            __builtin_amdgcn_s_barrier();
            __builtin_amdgcn_s_setprio(1);
#pragma unroll
            for (int i = 0; i < 4; ++i)
#pragma unroll
                for (int j = 0; j < 4; ++j)
                    acc[i][j] = __builtin_amdgcn_mfma_f32_16x16x32_bf16(af[i], bf[j], acc[i][j], 0, 0, 0);
            __builtin_amdgcn_s_setprio(0);
            __builtin_amdgcn_s_barrier();
        }
        // end of K-tile: wait tile t+1 (oldest 6); tile t+2's 6 stay in flight
        if (t < 30)       asm volatile("s_waitcnt vmcnt(6)" ::: "memory");
        else if (t == 30) asm volatile("s_waitcnt vmcnt(0)" ::: "memory");
        buf = (buf == 2) ? 0 : buf + 1;
        bufn = (bufn == 2) ? 0 : bufn + 1;
    }

#pragma unroll
    for (int j = 0; j < 4; ++j) {
        int n = n0 + wc * 64 + j * 16 + l15;
        float bj = bias[n];
        float sn = 0.f, cs = 1.f, sgn = 0.f;
        if (MODE == 0) {
            int d = n & 127, h = (n >> 7) & 15;
            float inv = expf(-(float)(d >> 1) * (9.210340371976184f / 64.0f)); // 10000^(-2i/128)
            sincosf((float)h * inv, &sn, &cs);
            sgn = (d & 1) ? sn : -sn;
        }
#pragma unroll
        for (int i = 0; i < 4; ++i) {
            int mbase = m0 + wr * 64 + i * 16 + g * 4;
            if (MODE == 2) {
                // V^T: [B,H,D,T]; t = m varies along r -> 8B packed store
                int d = n & 127, hh = n >> 7;
                int b_ = mbase >> 11, t0 = mbase & 2047;
                ushort4_t w;
#pragma unroll
                for (int r = 0; r < 4; ++r) w[r] = f2b(acc[i][j][r] + bj);
                *reinterpret_cast<ushort4_t*>(
                    (ushort_t*)Cv + (((size_t)(b_ * 16 + hh) * 128 + d) * 2048 + t0)) = w;
            } else if (MODE == 0) {
#pragma unroll
                for (int r = 0; r < 4; ++r) {
                    int m = mbase + r;
                    float v = acc[i][j][r] + bj;
                    float p = __shfl_xor(v, 1, 64);   // d-pair partner (adjacent lane)
                    v = fmaf(p, sgn, v * cs);         // even: v*cs - p*sn ; odd: v*cs + p*sn
                    v *= oscale;
                    size_t addr = ((size_t)((m >> 11) * 16 + (n >> 7)) * 2048 + (m & 2047)) * 128 + (n & 127);
                    ((ushort_t*)Cv)[addr] = f2b(v);
                }
            } else {
#pragma unroll
                for (int r = 0; r < 4; ++r)
                    ((float*)Cv)[(size_t)(mbase + r) * 2048 + n] = acc[i][j][r] + bj;
            }
        }
    }
}

// ---------------- flash attention (R11-proven): swapped-QK^T, permlane P-redistribution ----------------
// grid (T/128, H, B); 8 waves x 16 q-rows. K[B,H,T,D], Vt[B,H,D,T]. Out [B*T][2048] bf16.
// Q pre-scaled by (1/sqrt(128))*log2(e) -> P = exp2(s - m).
// K rows presented to QK^T via sigma (swap l15 quarters 1<->2): group g holds
// kv 4*qmap(g)+r (qmap={0,2,1,3}) -> PV B-frags assembled with 2 permlane32_swap per
// 32-kv chunk (no ds_bpermute). l accumulated via ones-row MFMA.
__global__ __launch_bounds__(512)
void fattn(const ushort_t* __restrict__ Q, const ushort_t* __restrict__ K,
           const ushort_t* __restrict__ Vt, ushort_t* __restrict__ O) {
    __shared__ __align__(16) ushort_t Ks[2][64 * 128];   // [kv][d] swizzled
    __shared__ __align__(16) ushort_t Vs[2][128 * 64];   // [d][kv] swizzled
    const int tid = threadIdx.x, lane = tid & 63, wid = tid >> 6;
    const int l15 = lane & 15, g = lane >> 4;
    const int h = blockIdx.y, b = blockIdx.z;
    const size_t base = ((size_t)b * 16 + h) * (2048 * 128);
    const int q0 = blockIdx.x * 128 + wid * 16;
    // sigma: A-row l15 -> physical K row (swap quarters 1 and 2)
    const int q2 = l15 >> 2;
    const int sig = ((q2 == 1) ? 2 : (q2 == 2) ? 1 : q2) * 4 + (l15 & 3);
    short8 qf[4];
#pragma unroll
    for (int c = 0; c < 4; ++c)
        qf[c] = *reinterpret_cast<const short8*>(Q + base + (size_t)(q0 + l15) * 128 + c * 32 + g * 8);
    f32x4 oacc[8] = {};
    f32x4 oaccL = {};                  // ones-row: running column-sum of P
    float m_r = -__builtin_inff();
    short8 ones;
#pragma unroll
    for (int j = 0; j < 8; ++j) ones[j] = (short)0x3F80;   // bf16 1.0

    auto stage = [&](int kv0, int bsel) {
#pragma unroll
        for (int is = 0; is < 2; ++is) {
            {   // K tile [64][128]: 16 chunks/row
                int c = is * 512 + tid;
                int row = c >> 4, sub = c & 15;
                int dsrc = (sub ^ (row & 7)) << 3;
                gload16(K + base + (size_t)(kv0 + row) * 128 + dsrc,
                        (char*)Ks[bsel] + (size_t)c * 16);
            }
            {   // Vt tile [128][64]: 8 chunks/row
                int c = is * 512 + tid;
                int row = c >> 3, sub = c & 7;
                int tsrc = (sub ^ (row & 7)) << 3;
                gload16(Vt + base + (size_t)row * 2048 + kv0 + tsrc,
                        (char*)Vs[bsel] + (size_t)c * 16);
            }
        }
    };

    stage(0, 0);
    asm volatile("s_waitcnt vmcnt(0)" ::: "memory");
    __builtin_amdgcn_s_barrier();

    for (int it = 0; it < 32; ++it) {
        const int cur = it & 1;
        if (it < 31) stage((it + 1) << 6, cur ^ 1);   // prefetch flies under compute
        // S'^T = K Q'^T (pre-scaled); A-row sigma-permuted
        f32x4 s[4] = {};
        __builtin_amdgcn_s_setprio(1);
#pragma unroll
        for (int nt = 0; nt < 4; ++nt) {
            int kvr = nt * 16 + sig;
#pragma unroll
            for (int c = 0; c < 4; ++c) {
                short8 kf = *reinterpret_cast<const short8*>(
                    (const char*)Ks[cur] + kvr * 256 + (((4 * c + g) ^ (sig & 7)) << 4));
                s[nt] = __builtin_amdgcn_mfma_f32_16x16x32_bf16(kf, qf[c], s[nt], 0, 0, 0);
            }
        }
        __builtin_amdgcn_s_setprio(0);
        // row max: 15 in-reg + 2 shfl
        float pm = fmaxf(fmaxf(fmaxf(s[0][0], s[0][1]), fmaxf(s[0][2], s[0][3])),
                         fmaxf(fmaxf(s[1][0], s[1][1]), fmaxf(s[1][2], s[1][3])));
        pm = fmaxf(pm, fmaxf(fmaxf(fmaxf(s[2][0], s[2][1]), fmaxf(s[2][2], s[2][3])),
                             fmaxf(fmaxf(s[3][0], s[3][1]), fmaxf(s[3][2], s[3][3]))));
        pm = fmaxf(pm, __shfl_xor(pm, 16, 64));
        pm = fmaxf(pm, __shfl_xor(pm, 32, 64));
        // defer-max (T13): rescale only when max grew past 5.0 (log2 units; p <= 32)
        if (!__all(pm <= m_r + 5.0f)) {
            float mn = fmaxf(m_r, pm);
            float fac = exp2f(m_r - mn);
            m_r = mn;
#pragma unroll
            for (int r = 0; r < 4; ++r) oaccL[r] *= fac;
#pragma unroll
            for (int nt2 = 0; nt2 < 8; ++nt2)
#pragma unroll
                for (int r = 0; r < 4; ++r) oacc[nt2][r] *= fac;
        }
        // P = exp2(s - m), pack via v_cvt_pk_bf16_f32
        uint_t W[4][2];
#pragma unroll
        for (int nt = 0; nt < 4; ++nt) {
            float p0 = exp2f(s[nt][0] - m_r);
            float p1 = exp2f(s[nt][1] - m_r);
            float p2 = exp2f(s[nt][2] - m_r);
            float p3 = exp2f(s[nt][3] - m_r);
            W[nt][0] = cvt_pk_bf16(p0, p1);
            W[nt][1] = cvt_pk_bf16(p2, p3);
        }
        // O^T += V^T P : B-frags via 2 permlane32_swap per 32-kv chunk
        __builtin_amdgcn_s_setprio(1);
#pragma unroll
        for (int ks = 0; ks < 2; ++ks) {
            uint_t A0 = W[2 * ks][0], A1 = W[2 * ks][1];
            uint_t B0 = W[2 * ks + 1][0], B1 = W[2 * ks + 1][1];
            asm("v_permlane32_swap_b32 %0, %1" : "+v"(A0), "+v"(B0));
            asm("v_permlane32_swap_b32 %0, %1" : "+v"(A1), "+v"(B1));
            uint4_t wv; wv[0] = A0; wv[1] = A1; wv[2] = B0; wv[3] = B1;
            short8 pb = __builtin_bit_cast(short8, wv);
            oaccL = __builtin_amdgcn_mfma_f32_16x16x32_bf16(ones, pb, oaccL, 0, 0, 0);
#pragma unroll
            for (int nt2 = 0; nt2 < 8; ++nt2) {
                int dr = nt2 * 16 + l15;
                short8 vb = *reinterpret_cast<const short8*>(
                    (const char*)Vs[cur] + dr * 128 + (((ks * 4 + g) ^ (dr & 7)) << 4));
                oacc[nt2] = __builtin_amdgcn_mfma_f32_16x16x32_bf16(vb, pb, oacc[nt2], 0, 0, 0);
            }
        }
        __builtin_amdgcn_s_setprio(0);
        asm volatile("s_waitcnt vmcnt(0)" ::: "memory");
        __builtin_amdgcn_s_barrier();
    }
    // every reg of oaccL holds colsum for q=l15 (ones-row rows are identical)
    float inv = 1.f / oaccL[0];
    const size_t orow = ((size_t)b * 2048 + q0 + l15) * 2048 + (size_t)h * 128;
#pragma unroll
    for (int nt2 = 0; nt2 < 8; ++nt2) {
        ushort4_t w;
#pragma unroll
        for (int r = 0; r < 4; ++r) w[r] = f2b(oacc[nt2][r] * inv);
        *reinterpret_cast<ushort4_t*>(O + orow + nt2 * 16 + g * 4) = w;
    }
}

extern "C" void kernel_launch(void* const* d_in, const int* in_sizes, int n_in,
                              void* d_out, int out_size, void* d_ws, size_t ws_size,
                              hipStream_t stream) {
    const float* x  = (const float*)d_in[0];
    const float* Wq = (const float*)d_in[1];
    const float* bq = (const float*)d_in[2];
    const float* Wk = (const float*)d_in[3];
    const float* bk = (const float*)d_in[4];
    const float* Wv = (const float*)d_in[5];
    const float* bv = (const float*)d_in[6];
    const float* Wo = (const float*)d_in[7];
    const float* bo = (const float*)d_in[8];
    float* out = (float*)d_out;
    ushort_t* ws  = (ushort_t*)d_ws;

    const size_t WSZ = 2048ull * 2048;          // weight elems (4.19M)
    const size_t TSZ = 2ull * 16 * 2048 * 128;  // tensor elems (8.39M)
    ushort_t* xb  = ws;            // bf16 x
    ushort_t* Wtq = xb + TSZ;
    ushort_t* Wtk = Wtq + WSZ;
    ushort_t* Wtv = Wtk + WSZ;
    ushort_t* Wto = Wtv + WSZ;
    ushort_t* Qb  = Wto + WSZ;
    ushort_t* Kb  = Qb + TSZ;
    ushort_t* Vtb = Kb + TSZ;
    ushort_t* Sb  = Vtb + TSZ;   // attention output

    const float QSC = 0.08838834764831845f * 1.4426950408889634f; // (1/sqrt(128))*log2(e)

    cast_bf16<<<dim3(4096), 256, 0, stream>>>(x, xb);
    transp4<<<dim3(32, 32, 4), 64, 0, stream>>>(Wq, Wk, Wv, Wo, Wtq, Wtk, Wtv, Wto);

    gemm_p<0><<<dim3(8, 32), 512, 0, stream>>>(xb, Wtq, bq, Qb, QSC);
    gemm_p<0><<<dim3(8, 32), 512, 0, stream>>>(xb, Wtk, bk, Kb, 1.0f);
    gemm_p<2><<<dim3(8, 32), 512, 0, stream>>>(xb, Wtv, bv, Vtb, 1.0f);

    fattn<<<dim3(16, 16, 2), 512, 0, stream>>>(Qb, Kb, Vtb, Sb);

    gemm_p<3><<<dim3(8, 32), 512, 0, stream>>>(Sb, Wto, bo, out, 1.0f);
}

// Round 15
// 297.353 us; speedup vs baseline: 1.3094x; 1.3094x over previous
//
#include <hip/hip_runtime.h>

typedef unsigned short ushort_t;
typedef unsigned int uint_t;
typedef __attribute__((ext_vector_type(8))) short short8;   // 8 x bf16 bits
typedef __attribute__((ext_vector_type(4))) float f32x4;
typedef __attribute__((ext_vector_type(4))) unsigned short ushort4_t;
typedef __attribute__((ext_vector_type(4))) unsigned int uint4_t;

__device__ inline ushort_t f2b(float f) {
    unsigned int x = __builtin_bit_cast(unsigned int, f);
    x += 0x7fffu + ((x >> 16) & 1u);   // RNE
    return (ushort_t)(x >> 16);
}
__device__ inline uint_t cvt_pk_bf16(float lo, float hi) {
    uint_t r;
    asm("v_cvt_pk_bf16_f32 %0, %1, %2" : "=v"(r) : "v"(lo), "v"(hi));
    return r;   // low16 = bf16(lo), high16 = bf16(hi)
}

__device__ inline void gload16(const void* g, void* l) {
    __builtin_amdgcn_global_load_lds(
        (const __attribute__((address_space(1))) void*)g,
        (__attribute__((address_space(3))) void*)l, 16, 0, 0);
}

// XCD-chunked bijective swizzle for nwg=512 (512 % 8 == 0): each XCD gets 64
// consecutive logical blocks -> shared panels/heads stay in one L2. [T1]
__device__ inline int xcd_swz512(int bid) {
    return (bid & 7) * 64 + (bid >> 3);
}

// ---------------- fp32 -> bf16 cast (8 elems/thread) ----------------
__global__ __launch_bounds__(256)
void cast_bf16(const float* __restrict__ src, ushort_t* __restrict__ dst) {
    size_t i = ((size_t)blockIdx.x * 256 + threadIdx.x) * 8;
    f32x4 a = *reinterpret_cast<const f32x4*>(src + i);
    f32x4 b = *reinterpret_cast<const f32x4*>(src + i + 4);
    short8 v;
#pragma unroll
    for (int j = 0; j < 4; ++j) { v[j] = (short)f2b(a[j]); v[4 + j] = (short)f2b(b[j]); }
    *reinterpret_cast<short8*>(dst + i) = v;
}

// ---------------- batched 2048x2048 fp32->bf16 transpose (4 weight matrices) ----------------
__global__ __launch_bounds__(64)
void transp4(const float* __restrict__ s0, const float* __restrict__ s1,
             const float* __restrict__ s2, const float* __restrict__ s3,
             ushort_t* __restrict__ d0, ushort_t* __restrict__ d1,
             ushort_t* __restrict__ d2, ushort_t* __restrict__ d3) {
    const int z = blockIdx.z;
    const float* src = (z == 0) ? s0 : (z == 1) ? s1 : (z == 2) ? s2 : s3;
    ushort_t* dst = (z == 0) ? d0 : (z == 1) ? d1 : (z == 2) ? d2 : d3;
    const int R = 2048, C = 2048;
    int r0 = blockIdx.x * 64 + ((threadIdx.x >> 3) << 3);
    int c0 = blockIdx.y * 64 + ((threadIdx.x & 7) << 3);
    ushort_t v[8][8];
#pragma unroll
    for (int i = 0; i < 8; ++i) {
        const float* p = src + (size_t)(r0 + i) * C + c0;
        f32x4 a = *reinterpret_cast<const f32x4*>(p);
        f32x4 b = *reinterpret_cast<const f32x4*>(p + 4);
#pragma unroll
        for (int j = 0; j < 4; ++j) { v[i][j] = f2b(a[j]); v[i][4 + j] = f2b(b[j]); }
    }
#pragma unroll
    for (int c = 0; c < 8; ++c) {
        short8 w;
#pragma unroll
        for (int i = 0; i < 8; ++i) w[i] = (short)v[i][c];
        *reinterpret_cast<short8*>(dst + (size_t)(c0 + c) * R + r0) = w;
    }
}

// ---------------- QKV GEMM (R11-proven 128^2 tile + XCD swizzle) ----------------
// 1D grid 512. MODE 0: rope(+oscale) -> [B,H,T,D] (Q/K); MODE 2: V^T -> [B,H,D,T].
template <int MODE>
__global__ __launch_bounds__(256)
void gemm_qkv(const ushort_t* __restrict__ A, const ushort_t* __restrict__ Bt,
              const float* __restrict__ bias, ushort_t* __restrict__ C, float oscale) {
    const int K = 2048;
    __shared__ __align__(16) ushort_t As[128 * 64];
    __shared__ __align__(16) ushort_t Bs[128 * 64];
    const int tid = threadIdx.x, lane = tid & 63, wid = tid >> 6;
    const int l15 = lane & 15, g = lane >> 4;
    const int wr = wid >> 1, wc = wid & 1;
    const int lin = xcd_swz512(blockIdx.x);
    const int m0 = (lin >> 4) * 128, n0 = (lin & 15) * 128;
    f32x4 acc[4][4] = {};
    for (int k0 = 0; k0 < K; k0 += 64) {
#pragma unroll
        for (int is = 0; is < 4; ++is) {
            int c = is * 256 + tid;
            int row = c >> 3, sub = c & 7;
            int ks = (sub ^ (row & 7)) << 3;   // pre-swizzled global source (involution)
            char* ldst = (char*)As + (size_t)(is * 256 + wid * 64) * 16;
            gload16(A + (size_t)(m0 + row) * K + k0 + ks, ldst);
            char* ldstB = (char*)Bs + (size_t)(is * 256 + wid * 64) * 16;
            gload16(Bt + (size_t)(n0 + row) * K + k0 + ks, ldstB);
        }
        __syncthreads();
#pragma unroll
        for (int kk = 0; kk < 2; ++kk) {
            short8 af[4], bf[4];
#pragma unroll
            for (int i = 0; i < 4; ++i) {
                int ra = wr * 64 + i * 16 + l15;
                af[i] = *reinterpret_cast<const short8*>(
                    (const char*)As + ra * 128 + (((4 * kk + g) ^ (ra & 7)) << 4));
                int rb = wc * 64 + i * 16 + l15;
                bf[i] = *reinterpret_cast<const short8*>(
                    (const char*)Bs + rb * 128 + (((4 * kk + g) ^ (rb & 7)) << 4));
            }
#pragma unroll
            for (int i = 0; i < 4; ++i)
#pragma unroll
                for (int j = 0; j < 4; ++j)
                    acc[i][j] = __builtin_amdgcn_mfma_f32_16x16x32_bf16(af[i], bf[j], acc[i][j], 0, 0, 0);
        }
        __syncthreads();
    }
#pragma unroll
    for (int j = 0; j < 4; ++j) {
        int n = n0 + wc * 64 + j * 16 + l15;
        float bj = bias[n];
        float sn = 0.f, cs = 1.f, sgn = 0.f;
        if (MODE == 0) {
            int d = n & 127, h = (n >> 7) & 15;
            float inv = expf(-(float)(d >> 1) * (9.210340371976184f / 64.0f)); // 10000^(-2i/128)
            sincosf((float)h * inv, &sn, &cs);
            sgn = (d & 1) ? sn : -sn;
        }
#pragma unroll
        for (int i = 0; i < 4; ++i) {
            int mbase = m0 + wr * 64 + i * 16 + g * 4;
            if (MODE == 2) {
                // V^T: [B,H,D,T]; t = m varies along r -> 8B packed store
                int d = n & 127, hh = n >> 7;
                int b_ = mbase >> 11, t0 = mbase & 2047;
                ushort4_t w;
#pragma unroll
                for (int r = 0; r < 4; ++r) w[r] = f2b(acc[i][j][r] + bj);
                *reinterpret_cast<ushort4_t*>(
                    C + (((size_t)(b_ * 16 + hh) * 128 + d) * 2048 + t0)) = w;
            } else {
#pragma unroll
                for (int r = 0; r < 4; ++r) {
                    int m = mbase + r;
                    float v = acc[i][j][r] + bj;
                    float p = __shfl_xor(v, 1, 64);   // d-pair partner (adjacent lane)
                    v = fmaf(p, sgn, v * cs);         // even: v*cs - p*sn ; odd: v*cs + p*sn
                    v *= oscale;
                    size_t addr = ((size_t)((m >> 11) * 16 + (n >> 7)) * 2048 + (m & 2047)) * 128 + (n & 127);
                    C[addr] = f2b(v);
                }
            }
        }
    }
}

// ---------------- out-proj GEMM: C[M][N] fp32 = A @ Bt^T + bias (+ XCD swizzle) ----------------
__global__ __launch_bounds__(256)
void gemm_out(const ushort_t* __restrict__ A, const ushort_t* __restrict__ Bt,
              const float* __restrict__ bias, float* __restrict__ C,
              int M, int N, int K) {
    __shared__ __align__(16) ushort_t As[128 * 64];
    __shared__ __align__(16) ushort_t Bs[128 * 64];
    const int tid = threadIdx.x, lane = tid & 63, wid = tid >> 6;
    const int l15 = lane & 15, g = lane >> 4;
    const int wr = wid >> 1, wc = wid & 1;
    const int lin = xcd_swz512(blockIdx.x);
    const int m0 = (lin >> 4) * 128, n0 = (lin & 15) * 128;
    f32x4 acc[4][4] = {};
    for (int k0 = 0; k0 < K; k0 += 64) {
#pragma unroll
        for (int is = 0; is < 4; ++is) {
            int c = is * 256 + tid;
            int row = c >> 3, sub = c & 7;
            int ks = (sub ^ (row & 7)) << 3;
            char* ldst = (char*)As + (size_t)(is * 256 + wid * 64) * 16;
            gload16(A + (size_t)(m0 + row) * K + k0 + ks, ldst);
            char* ldstB = (char*)Bs + (size_t)(is * 256 + wid * 64) * 16;
            gload16(Bt + (size_t)(n0 + row) * K + k0 + ks, ldstB);
        }
        __syncthreads();
#pragma unroll
        for (int kk = 0; kk < 2; ++kk) {
            short8 af[4], bf[4];
#pragma unroll
            for (int i = 0; i < 4; ++i) {
                int ra = wr * 64 + i * 16 + l15;
                af[i] = *reinterpret_cast<const short8*>(
                    (const char*)As + ra * 128 + (((4 * kk + g) ^ (ra & 7)) << 4));
                int rb = wc * 64 + i * 16 + l15;
                bf[i] = *reinterpret_cast<const short8*>(
                    (const char*)Bs + rb * 128 + (((4 * kk + g) ^ (rb & 7)) << 4));
            }
#pragma unroll
            for (int i = 0; i < 4; ++i)
#pragma unroll
                for (int j = 0; j < 4; ++j)
                    acc[i][j] = __builtin_amdgcn_mfma_f32_16x16x32_bf16(af[i], bf[j], acc[i][j], 0, 0, 0);
        }
        __syncthreads();
    }
#pragma unroll
    for (int j = 0; j < 4; ++j) {
        int n = n0 + wc * 64 + j * 16 + l15;
        float bj = bias[n];
#pragma unroll
        for (int i = 0; i < 4; ++i) {
            int mbase = m0 + wr * 64 + i * 16 + g * 4;
#pragma unroll
            for (int r = 0; r < 4; ++r)
                C[(size_t)(mbase + r) * N + n] = acc[i][j][r] + bj;
        }
    }
}

// ---------------- flash attention (R11-proven) + XCD swizzle ----------------
// 1D grid 512 -> (q-tile, head, batch); 8 waves x 16 q-rows. K[B,H,T,D], Vt[B,H,D,T].
// Q pre-scaled by (1/sqrt(128))*log2(e) -> P = exp2(s - m).
// K rows presented to QK^T via sigma (swap l15 quarters 1<->2): group g holds
// kv 4*qmap(g)+r (qmap={0,2,1,3}) -> PV B-frags assembled with 2 permlane32_swap per
// 32-kv chunk (no ds_bpermute). l accumulated via ones-row MFMA.
__global__ __launch_bounds__(512)
void fattn(const ushort_t* __restrict__ Q, const ushort_t* __restrict__ K,
           const ushort_t* __restrict__ Vt, ushort_t* __restrict__ O) {
    __shared__ __align__(16) ushort_t Ks[2][64 * 128];   // [kv][d] swizzled
    __shared__ __align__(16) ushort_t Vs[2][128 * 64];   // [d][kv] swizzled
    const int tid = threadIdx.x, lane = tid & 63, wid = tid >> 6;
    const int l15 = lane & 15, g = lane >> 4;
    const int lin = xcd_swz512(blockIdx.x);
    const int qt = lin & 15, h = (lin >> 4) & 15, b = lin >> 8;
    const size_t base = ((size_t)b * 16 + h) * (2048 * 128);
    const int q0 = qt * 128 + wid * 16;
    // sigma: A-row l15 -> physical K row (swap quarters 1 and 2)
    const int q2 = l15 >> 2;
    const int sig = ((q2 == 1) ? 2 : (q2 == 2) ? 1 : q2) * 4 + (l15 & 3);
    short8 qf[4];
#pragma unroll
    for (int c = 0; c < 4; ++c)
        qf[c] = *reinterpret_cast<const short8*>(Q + base + (size_t)(q0 + l15) * 128 + c * 32 + g * 8);
    f32x4 oacc[8] = {};
    f32x4 oaccL = {};                  // ones-row: running column-sum of P
    float m_r = -__builtin_inff();
    short8 ones;
#pragma unroll
    for (int j = 0; j < 8; ++j) ones[j] = (short)0x3F80;   // bf16 1.0

    auto stage = [&](int kv0, int bsel) {
#pragma unroll
        for (int is = 0; is < 2; ++is) {
            {   // K tile [64][128]: 16 chunks/row
                int c = is * 512 + tid;
                int row = c >> 4, sub = c & 15;
                int dsrc = (sub ^ (row & 7)) << 3;
                gload16(K + base + (size_t)(kv0 + row) * 128 + dsrc,
                        (char*)Ks[bsel] + (size_t)c * 16);
            }
            {   // Vt tile [128][64]: 8 chunks/row
                int c = is * 512 + tid;
                int row = c >> 3, sub = c & 7;
                int tsrc = (sub ^ (row & 7)) << 3;
                gload16(Vt + base + (size_t)row * 2048 + kv0 + tsrc,
                        (char*)Vs[bsel] + (size_t)c * 16);
            }
        }
    };

    stage(0, 0);
    asm volatile("s_waitcnt vmcnt(0)" ::: "memory");
    __builtin_amdgcn_s_barrier();

    for (int it = 0; it < 32; ++it) {
        const int cur = it & 1;
        if (it < 31) stage((it + 1) << 6, cur ^ 1);   // prefetch flies under compute
        // S'^T = K Q'^T (pre-scaled); A-row sigma-permuted
        f32x4 s[4] = {};
        __builtin_amdgcn_s_setprio(1);
#pragma unroll
        for (int nt = 0; nt < 4; ++nt) {
            int kvr = nt * 16 + sig;
#pragma unroll
            for (int c = 0; c < 4; ++c) {
                short8 kf = *reinterpret_cast<const short8*>(
                    (const char*)Ks[cur] + kvr * 256 + (((4 * c + g) ^ (sig & 7)) << 4));
                s[nt] = __builtin_amdgcn_mfma_f32_16x16x32_bf16(kf, qf[c], s[nt], 0, 0, 0);
            }
        }
        __builtin_amdgcn_s_setprio(0);
        // row max: 15 in-reg + 2 shfl
        float pm = fmaxf(fmaxf(fmaxf(s[0][0], s[0][1]), fmaxf(s[0][2], s[0][3])),
                         fmaxf(fmaxf(s[1][0], s[1][1]), fmaxf(s[1][2], s[1][3])));
        pm = fmaxf(pm, fmaxf(fmaxf(fmaxf(s[2][0], s[2][1]), fmaxf(s[2][2], s[2][3])),
                             fmaxf(fmaxf(s[3][0], s[3][1]), fmaxf(s[3][2], s[3][3]))));
        pm = fmaxf(pm, __shfl_xor(pm, 16, 64));
        pm = fmaxf(pm, __shfl_xor(pm, 32, 64));
        // defer-max (T13): rescale only when max grew past 5.0 (log2 units; p <= 32)
        if (!__all(pm <= m_r + 5.0f)) {
            float mn = fmaxf(m_r, pm);
            float fac = exp2f(m_r - mn);
            m_r = mn;
#pragma unroll
            for (int r = 0; r < 4; ++r) oaccL[r] *= fac;
#pragma unroll
            for (int nt2 = 0; nt2 < 8; ++nt2)
#pragma unroll
                for (int r = 0; r < 4; ++r) oacc[nt2][r] *= fac;
        }
        // P = exp2(s - m), pack via v_cvt_pk_bf16_f32
        uint_t W[4][2];
#pragma unroll
        for (int nt = 0; nt < 4; ++nt) {
            float p0 = exp2f(s[nt][0] - m_r);
            float p1 = exp2f(s[nt][1] - m_r);
            float p2 = exp2f(s[nt][2] - m_r);
            float p3 = exp2f(s[nt][3] - m_r);
            W[nt][0] = cvt_pk_bf16(p0, p1);
            W[nt][1] = cvt_pk_bf16(p2, p3);
        }
        // O^T += V^T P : B-frags via 2 permlane32_swap per 32-kv chunk
        __builtin_amdgcn_s_setprio(1);
#pragma unroll
        for (int ks = 0; ks < 2; ++ks) {
            uint_t A0 = W[2 * ks][0], A1 = W[2 * ks][1];
            uint_t B0 = W[2 * ks + 1][0], B1 = W[2 * ks + 1][1];
            asm("v_permlane32_swap_b32 %0, %1" : "+v"(A0), "+v"(B0));
            asm("v_permlane32_swap_b32 %0, %1" : "+v"(A1), "+v"(B1));
            uint4_t wv; wv[0] = A0; wv[1] = A1; wv[2] = B0; wv[3] = B1;
            short8 pb = __builtin_bit_cast(short8, wv);
            oaccL = __builtin_amdgcn_mfma_f32_16x16x32_bf16(ones, pb, oaccL, 0, 0, 0);
#pragma unroll
            for (int nt2 = 0; nt2 < 8; ++nt2) {
                int dr = nt2 * 16 + l15;
                short8 vb = *reinterpret_cast<const short8*>(
                    (const char*)Vs[cur] + dr * 128 + (((ks * 4 + g) ^ (dr & 7)) << 4));
                oacc[nt2] = __builtin_amdgcn_mfma_f32_16x16x32_bf16(vb, pb, oacc[nt2], 0, 0, 0);
            }
        }
        __builtin_amdgcn_s_setprio(0);
        asm volatile("s_waitcnt vmcnt(0)" ::: "memory");
        __builtin_amdgcn_s_barrier();
    }
    // every reg of oaccL holds colsum for q=l15 (ones-row rows are identical)
    float inv = 1.f / oaccL[0];
    const size_t orow = ((size_t)b * 2048 + q0 + l15) * 2048 + (size_t)h * 128;
#pragma unroll
    for (int nt2 = 0; nt2 < 8; ++nt2) {
        ushort4_t w;
#pragma unroll
        for (int r = 0; r < 4; ++r) w[r] = f2b(oacc[nt2][r] * inv);
        *reinterpret_cast<ushort4_t*>(O + orow + nt2 * 16 + g * 4) = w;
    }
}

extern "C" void kernel_launch(void* const* d_in, const int* in_sizes, int n_in,
                              void* d_out, int out_size, void* d_ws, size_t ws_size,
                              hipStream_t stream) {
    const float* x  = (const float*)d_in[0];
    const float* Wq = (const float*)d_in[1];
    const float* bq = (const float*)d_in[2];
    const float* Wk = (const float*)d_in[3];
    const float* bk = (const float*)d_in[4];
    const float* Wv = (const float*)d_in[5];
    const float* bv = (const float*)d_in[6];
    const float* Wo = (const float*)d_in[7];
    const float* bo = (const float*)d_in[8];
    float* out = (float*)d_out;
    ushort_t* ws  = (ushort_t*)d_ws;

    const size_t WSZ = 2048ull * 2048;          // weight elems (4.19M)
    const size_t TSZ = 2ull * 16 * 2048 * 128;  // tensor elems (8.39M)
    ushort_t* xb  = ws;            // bf16 x
    ushort_t* Wtq = xb + TSZ;
    ushort_t* Wtk = Wtq + WSZ;
    ushort_t* Wtv = Wtk + WSZ;
    ushort_t* Wto = Wtv + WSZ;
    ushort_t* Qb  = Wto + WSZ;
    ushort_t* Kb  = Qb + TSZ;
    ushort_t* Vtb = Kb + TSZ;
    ushort_t* Sb  = Vtb + TSZ;   // attention output

    const float QSC = 0.08838834764831845f * 1.4426950408889634f; // (1/sqrt(128))*log2(e)

    cast_bf16<<<dim3(4096), 256, 0, stream>>>(x, xb);
    transp4<<<dim3(32, 32, 4), 64, 0, stream>>>(Wq, Wk, Wv, Wo, Wtq, Wtk, Wtv, Wto);

    gemm_qkv<0><<<dim3(512), 256, 0, stream>>>(xb, Wtq, bq, Qb, QSC);
    gemm_qkv<0><<<dim3(512), 256, 0, stream>>>(xb, Wtk, bk, Kb, 1.0f);
    gemm_qkv<2><<<dim3(512), 256, 0, stream>>>(xb, Wtv, bv, Vtb, 1.0f);

    fattn<<<dim3(512), 512, 0, stream>>>(Qb, Kb, Vtb, Sb);

    gemm_out<<<dim3(512), 256, 0, stream>>>(Sb, Wto, bo, out, 4096, 2048, 2048);
}